// Round 12
// baseline (232.455 us; speedup 1.0000x reference)
//
#include <hip/hip_runtime.h>
#include <hip/hip_bf16.h>

// ---------------------------------------------------------------------------
// InferCellV2 R17: R16's paired source-major kernels x 2 blocks/CU.
// R16 post-mortem: 256-thr blocks DID get the VGPR grant (224, zero scratch,
// WRITE ideal) - the 128-cap is a 512-thr artifact. But 117KB LDS -> 1
// block/CU -> 1 wave/SIMD (Occupancy 9%): no latency hiding, conv_k 43us,
// MfmaUtil stuck 24%. R12 had 8 waves/CU (hiding) but 2x LDS demand; R16
// had half the LDS demand but no hiding. R17 combines: A 43.5KB + B as
// R8's proven 2-tap ping-pong groups (2x16KB) = 76288B -> 2 blocks/CU =
// 8 waves/CU = 2 waves/SIMD (VGPR budget still 256/wave). Groups chain
// continuously across phases (stage E3g0 while computing E0g4 - no serial
// B restage); 1 barrier/group; sibling block desyncs to cover stalls.
// Model: paired step = 4 A ds_read + 4 LDS-B ds_read + 8 reg-B global
// per wave per 32 MFMA -> 8 waves: LDS 384cyc vs MFMA 310cyc -> ~45%
// MfmaUtil ceiling WITH latency hiding.
// K1(r0): paired E0(LDS-B)+E1(reg-B wtR) -> node1,p2; chain single E3 -> p3.
// K2(r1): paired E2+E4 -> node2,p3.  K3(r2): single E5 -> fp32 out.
// Verified pieces byte-kept: A layout/swizzle/ldA, ldB frag math, frag-major
// wtR reg-B (R13b), oc-permute + node/f32 epilogues (R11+), partial record
// roundtrip (R15/R16), pre_kernel (R15/R16), R8 group staging pattern.
// ---------------------------------------------------------------------------

typedef __bf16 bf16x8 __attribute__((ext_vector_type(8)));
typedef float floatx4 __attribute__((ext_vector_type(4)));
typedef unsigned int uint32;
typedef uint32 u32x4 __attribute__((ext_vector_type(4)));
#define AS1 __attribute__((address_space(1)))

#define PADW 34
#define PIMG (PADW * PADW)
#define ROWB (PADW * 64 * 2)        // 4352 B per padded NHWC row
#define A_LDS (10 * ROWB)           // 43520 (8 out rows + 2 halo)
#define A_CHUNKS (A_LDS / 16)       // 2720 = 10*256 + 160
#define A_TAIL (A_CHUNKS - 10 * 256)// 160
#define TAPB (64 * 64 * 2)          // 8192 B per weight tap
#define GRPB (2 * TAPB)             // 16384 B per 2-tap group buffer
#define SMEM_BYTES (A_LDS + 2 * GRPB) // 76288 -> 2 blocks/CU

__device__ __forceinline__ void gld16(const char* g, char* l) {
    __builtin_amdgcn_global_load_lds(
        (const AS1 uint32*)g, (__attribute__((address_space(3))) uint32*)l,
        16, 0, 0);
}

// ---------------- fused pre-pass: weights (2 layouts) + halo + relu_pad -----
__global__ __launch_bounds__(256) void pre_kernel(
    const float* __restrict__ in, const float* __restrict__ a1,
    const float* __restrict__ a2, const float* __restrict__ W,
    __hip_bfloat16* __restrict__ wt, __hip_bfloat16* __restrict__ wtR,
    __hip_bfloat16* __restrict__ r0, __hip_bfloat16* __restrict__ r1,
    __hip_bfloat16* __restrict__ r2) {
    __shared__ float tile[32][65];
    int blk = blockIdx.x;
    int tid = threadIdx.x;

    if (blk < 864) {                 // ---- weights: scale + both layouts
        int idx = blk * 256 + tid;   // 6*9*64*64 = 221184 exact
        int i = idx & 63;
        int o = (idx >> 6) & 63;     // TRUE oc
        int rest = idx >> 12;
        int t = rest % 9;
        int l = rest / 9;
        int ji = i >> 3, jo = o >> 3;
        float ain = 0.f, aout = 0.f;
#pragma unroll
        for (int j = 0; j < 8; ++j) {
            ain  += (j >= ji) ? a1[j] : 0.f;
            aout += (j >= jo) ? a2[j] : 0.f;
        }
        float v = W[(size_t)((l * 64 + o) * 64 + i) * 9 + t] * ain * aout;
        int os = ((o & 3) << 4) + (o >> 2);      // oc-permute storage col
        size_t e = (size_t)(l * 9 + t) * 4096 + os * 64 +
                   ((((i >> 3) ^ (os & 7)) << 3) + (i & 7));
        __hip_bfloat16 bv = __float2bfloat16(v);
        wt[e] = bv;                  // layout 1 (LDS gld16 path)
        int n  = os >> 4, c15 = os & 15;
        int q  = i >> 5, quad = (i >> 3) & 3, ee = i & 7;
        int ln = (quad << 4) + c15;
        size_t e2 = (size_t)(l * 9 + t) * 4096 + (((q << 2) + n) << 9) +
                    (ln << 3) + ee;
        wtR[e2] = bv;                // layout 2 (frag-major reg path)
    } else if (blk < 992) {          // ---- zero halo ring, image b
        int b = blk - 864;
        __hip_bfloat16* bufs[3] = {r0, r1, r2};
#pragma unroll
        for (int f = 0; f < 3; ++f) {
            uint32* buf = (uint32*)(bufs[f] + (size_t)b * PIMG * 64);
            for (int idx = tid; idx < 132 * 32; idx += 256) {
                int slot = idx >> 5, u = idx & 31;
                int yy, xx;
                if (slot < 34)      { yy = 0;  xx = slot; }
                else if (slot < 68) { yy = 33; xx = slot - 34; }
                else { int s2 = slot - 68; yy = 1 + (s2 >> 1); xx = (s2 & 1) * 33; }
                buf[(size_t)(yy * PADW + xx) * 32 + u] = 0u;
            }
        }
    } else {                         // ---- relu(x) -> padded swizzled NHWC
        int rb = blk - 992;
        int b = rb >> 5, y = rb & 31;
        int x = tid & 31, c0 = tid >> 5;
        const float* ip = in + ((size_t)b * 64 * 32 + y) * 32 + x;
#pragma unroll
        for (int cc = 0; cc < 8; ++cc) {
            int c = cc * 8 + c0;
            tile[x][c] = fmaxf(ip[(size_t)c * 1024], 0.f);
        }
        __syncthreads();
        int j = tid & 7, xq = tid >> 3;
        int p = (b * PADW + y + 1) * PADW + 1 + xq;
        alignas(16) __hip_bfloat16 hv[8];
#pragma unroll
        for (int k = 0; k < 8; ++k)
            hv[k] = __float2bfloat16(tile[xq][j * 8 + k]);
        *(uint4*)((char*)r0 + (size_t)p * 128 + ((j ^ (p & 7)) << 4)) =
            *(const uint4*)hv;
    }
}

#define ZERO4(A_)                                                        \
    _Pragma("unroll") for (int m_ = 0; m_ < 4; ++m_)                     \
    _Pragma("unroll") for (int n_ = 0; n_ < 4; ++n_)                     \
        A_[m_][n_] = (floatx4){0.f, 0.f, 0.f, 0.f};

// ---------------- source-major conv kernels (256 thr, 2 blocks/CU) ---------
// Block: image b = blk>>2, strip y0 = (blk&3)*8. Wave wv(0..3): rows
// y0+2wv,+1. A-frag: l15 = px, quad*8+q*32 = in-ch. LDS-B frag: l15 =
// storage col (true oc = l15*4+n). C/D: M(pixel) = quad*4+r. Partials:
// thread-owned 128B records at (blk*256+tid)*128.
template <int MODE>
__global__ __launch_bounds__(256, 2) void conv_k(
    const __hip_bfloat16* __restrict__ Asrc,
    const __hip_bfloat16* __restrict__ wt,
    const __hip_bfloat16* __restrict__ wtR,
    __hip_bfloat16* __restrict__ nodeOut, float* __restrict__ finalOut,
    __hip_bfloat16* __restrict__ p2, __hip_bfloat16* __restrict__ p3) {
    extern __shared__ char smem[];               // A 43520 + 2x16384
    char* smemB = smem + A_LDS;
    int tid = threadIdx.x;
    int wv = tid >> 6, lane = tid & 63;
    int quad = lane >> 4, l15 = lane & 15;
    int blk = blockIdx.x;
    int b = blk >> 2, y0 = (blk & 3) << 3;
    const int Rb = b * PADW + y0;
    const size_t aOff = (size_t)Rb * PADW * 128;
    const size_t pbase = ((size_t)blk * 256 + tid) << 7;   // 128B record

    auto stage_A = [&]() {           // 10 padded rows, linear 16B DMA copy
        const char* gA = (const char*)Asrc + aOff;
#pragma unroll
        for (int it = 0; it < 11; ++it) {
            int c = it * 256 + tid;
            if (it < 10 || tid < A_TAIL)
                gld16(gA + (size_t)c * 16, smem + (it * 256 + wv * 64) * 16);
        }
    };
    // nt taps of edge l starting at tap0 -> group buffer dst
    auto stage_Bgrp = [&](int l, int tap0, int nt, char* dst) {
        const char* gB = (const char*)wt + ((size_t)l * 9 + tap0) * TAPB;
#pragma unroll
        for (int it = 0; it < 2 * nt; ++it) {
            int c = it * 256 + tid;
            gld16(gB + (size_t)c * 16, dst + (it * 256 + wv * 64) * 16);
        }
    };
    auto ldA = [&](int tl, int q, bf16x8 (&dst)[4]) {
        const int ky = tl / 3, kx = tl % 3;
#pragma unroll
        for (int m = 0; m < 4; ++m) {
            int arow = 2 * wv + (m >> 1) + ky;      // LDS row 0..9
            int apx  = ((m & 1) << 4) + l15 + kx;   // 0..33
            int R = Rb + arow;                      // global padded row
            int slot = ((q << 2) + quad) ^ ((2 * R + apx) & 7);
            dst[m] = *(const bf16x8*)(smem + arow * ROWB + apx * 128 +
                                      slot * 16);
        }
    };
    auto ldBb = [&](const char* bufB, int lt, int q, bf16x8 (&dst)[4]) {
#pragma unroll
        for (int n = 0; n < 4; ++n) {
            int o = (n << 4) + l15;                 // storage col
            int slot = ((q << 2) + quad) ^ (l15 & 7);
            dst[n] = *(const bf16x8*)(bufB + lt * TAPB + o * 128 +
                                      slot * 16);
        }
    };
    auto init_p = [&](floatx4 (&acc)[4][4], const __hip_bfloat16* p) {
#pragma unroll
        for (int c = 0; c < 8; ++c) {
            alignas(16) __hip_bfloat16 hv[8];
            *(uint4*)hv = *(const uint4*)((const char*)p + pbase + c * 16);
#pragma unroll
            for (int k = 0; k < 8; ++k) {
                int j = c * 8 + k;
                acc[j >> 4][(j >> 2) & 3][j & 3] = __bfloat162float(hv[k]);
            }
        }
    };
    auto epi_p = [&](floatx4 (&acc)[4][4], __hip_bfloat16* p) {
#pragma unroll
        for (int c = 0; c < 8; ++c) {
            alignas(16) __hip_bfloat16 hv[8];
#pragma unroll
            for (int k = 0; k < 8; ++k) {
                int j = c * 8 + k;
                hv[k] = __float2bfloat16(acc[j >> 4][(j >> 2) & 3][j & 3]);
            }
            *(uint4*)((char*)p + pbase + c * 16) = *(const uint4*)hv;
        }
    };
    auto epi_node = [&](floatx4 (&acc)[4][4], __hip_bfloat16* dst) {
#pragma unroll
        for (int m = 0; m < 4; ++m) {
            int row = y0 + 2 * wv + (m >> 1);
#pragma unroll
            for (int r = 0; r < 4; ++r) {
                int x = ((m & 1) << 4) + (quad << 2) + r;
                int p = (b * PADW + row + 1) * PADW + x + 1;
                alignas(8) __hip_bfloat16 hv[4];
#pragma unroll
                for (int n = 0; n < 4; ++n)
                    hv[n] = __float2bfloat16(fmaxf(acc[m][n][r], 0.f));
                char* d8 = (char*)dst + (size_t)p * 128 +
                           ((((l15 >> 1) ^ (p & 7)) << 4) + ((l15 & 1) << 3));
                *(uint2*)d8 = *(const uint2*)hv;
            }
        }
    };
    // paired group: nt taps (t0..) LDS-B from bufB -> accL, reg-B edge lR
    // (frag-major wtR, per-tap ping-pong Bb) -> accR; 1-deep Af/Bf pipeline.
    auto paired_group = [&](const char* bufB, int lR, int t0, int nt,
                            floatx4 (&accL)[4][4], floatx4 (&accR)[4][4]) {
        const char* gR = (const char*)wtR + (size_t)lR * 9 * TAPB;
        u32x4 Bb[2][8];
#pragma unroll
        for (int f = 0; f < 8; ++f)
            Bb[0][f] = *(const AS1 u32x4*)(gR + (size_t)t0 * TAPB +
                                           (f << 10) + (lane << 4));
        bf16x8 Af[2][4], Bf[2][4];
        ldA(t0, 0, Af[0]);
        ldBb(bufB, 0, 0, Bf[0]);
#pragma unroll
        for (int st = 0; st < 2 * nt; ++st) {
            const int pb = st & 1, lt = st >> 1;
            if (st + 1 < 2 * nt) {
                ldA(t0 + ((st + 1) >> 1), (st + 1) & 1, Af[pb ^ 1]);
                ldBb(bufB, (st + 1) >> 1, (st + 1) & 1, Bf[pb ^ 1]);
            }
            if (pb == 0 && lt + 1 < nt) {
#pragma unroll
                for (int f = 0; f < 8; ++f)
                    Bb[(lt + 1) & 1][f] = *(const AS1 u32x4*)
                        (gR + (size_t)(t0 + lt + 1) * TAPB + (f << 10) +
                         (lane << 4));
            }
            __builtin_amdgcn_s_setprio(1);
#pragma unroll
            for (int m = 0; m < 4; ++m)
#pragma unroll
                for (int n = 0; n < 4; ++n)
                    accL[m][n] = __builtin_amdgcn_mfma_f32_16x16x32_bf16(
                        Af[pb][m], Bf[pb][n], accL[m][n], 0, 0, 0);
#pragma unroll
            for (int n = 0; n < 4; ++n) {
                bf16x8 Br = __builtin_bit_cast(bf16x8,
                                               Bb[lt & 1][(pb << 2) + n]);
#pragma unroll
                for (int m = 0; m < 4; ++m)
                    accR[m][n] = __builtin_amdgcn_mfma_f32_16x16x32_bf16(
                        Af[pb][m], Br, accR[m][n], 0, 0, 0);
            }
            __builtin_amdgcn_s_setprio(0);
        }
    };
    auto single_group = [&](const char* bufB, int t0, int nt,
                            floatx4 (&acc)[4][4]) {
        bf16x8 Af[2][4], Bf[2][4];
        ldA(t0, 0, Af[0]);
        ldBb(bufB, 0, 0, Bf[0]);
#pragma unroll
        for (int st = 0; st < 2 * nt; ++st) {
            const int pb = st & 1;
            if (st + 1 < 2 * nt) {
                ldA(t0 + ((st + 1) >> 1), (st + 1) & 1, Af[pb ^ 1]);
                ldBb(bufB, (st + 1) >> 1, (st + 1) & 1, Bf[pb ^ 1]);
            }
            __builtin_amdgcn_s_setprio(1);
#pragma unroll
            for (int m = 0; m < 4; ++m)
#pragma unroll
                for (int n = 0; n < 4; ++n)
                    acc[m][n] = __builtin_amdgcn_mfma_f32_16x16x32_bf16(
                        Af[pb][m], Bf[pb][n], acc[m][n], 0, 0, 0);
            __builtin_amdgcn_s_setprio(0);
        }
    };

    if constexpr (MODE == 1) {
        stage_A();
        stage_Bgrp(0, 0, 2, smemB);          // E0 g0 -> buf0
        __syncthreads();
        floatx4 aT[4][4], aX[4][4];
        ZERO4(aT); ZERO4(aX);
#pragma unroll
        for (int g = 0; g < 5; ++g) {        // E0 paired phase (gc = g)
            char* cur = smemB + (g & 1) * GRPB;
            char* nxt = smemB + ((g + 1) & 1) * GRPB;
            if (g < 4) stage_Bgrp(0, 2 * (g + 1), (g + 1 == 4) ? 1 : 2, nxt);
            else       stage_Bgrp(3, 0, 2, nxt);   // chain into E3 phase
            __builtin_amdgcn_sched_barrier(0);
            paired_group(cur, 1, 2 * g, (g == 4) ? 1 : 2, aT, aX);
            __syncthreads();                 // next group resident
        }
        epi_node(aT, nodeOut);               // node1 = relu -> r1
        epi_p(aX, p2);
        floatx4 aY[4][4];
        ZERO4(aY);
#pragma unroll
        for (int g = 0; g < 5; ++g) {        // E3 single phase (gc = 5+g)
            char* cur = smemB + ((5 + g) & 1) * GRPB;
            char* nxt = smemB + ((6 + g) & 1) * GRPB;
            if (g < 4) stage_Bgrp(3, 2 * (g + 1), (g + 1 == 4) ? 1 : 2, nxt);
            __builtin_amdgcn_sched_barrier(0);
            single_group(cur, 2 * g, (g == 4) ? 1 : 2, aY);
            if (g < 4) __syncthreads();
        }
        epi_p(aY, p3);
    } else if constexpr (MODE == 2) {
        stage_A();
        stage_Bgrp(2, 0, 2, smemB);          // E2 g0 -> buf0
        __syncthreads();
        floatx4 aX[4][4], aY[4][4];
        init_p(aX, p2);
        init_p(aY, p3);
#pragma unroll
        for (int g = 0; g < 5; ++g) {
            char* cur = smemB + (g & 1) * GRPB;
            char* nxt = smemB + ((g + 1) & 1) * GRPB;
            if (g < 4) stage_Bgrp(2, 2 * (g + 1), (g + 1 == 4) ? 1 : 2, nxt);
            __builtin_amdgcn_sched_barrier(0);
            paired_group(cur, 4, 2 * g, (g == 4) ? 1 : 2, aX, aY);
            if (g < 4) __syncthreads();
        }
        epi_node(aX, nodeOut);               // node2 = relu -> r2
        epi_p(aY, p3);
    } else {
        stage_A();
        stage_Bgrp(5, 0, 2, smemB);          // E5 g0 -> buf0
        __syncthreads();
        floatx4 aY[4][4];
        init_p(aY, p3);
#pragma unroll
        for (int g = 0; g < 5; ++g) {
            char* cur = smemB + (g & 1) * GRPB;
            char* nxt = smemB + ((g + 1) & 1) * GRPB;
            if (g < 4) stage_Bgrp(5, 2 * (g + 1), (g + 1 == 4) ? 1 : 2, nxt);
            __builtin_amdgcn_sched_barrier(0);
            single_group(cur, 2 * g, (g == 4) ? 1 : 2, aY);
            if (g < 4) __syncthreads();
        }
        // fp32 NCHW epilogue (oc = l15*4+n, verified R11/R12)
#pragma unroll
        for (int m = 0; m < 4; ++m) {
            int row = y0 + 2 * wv + (m >> 1);
#pragma unroll
            for (int n = 0; n < 4; ++n) {
                int o = (l15 << 2) + n;
                *(floatx4*)(finalOut +
                            (((size_t)b * 64 + o) * 32 + row) * 32 +
                            ((m & 1) << 4) + (quad << 2)) = aY[m][n];
            }
        }
    }
}

// ---------------------------------------------------------------------------
extern "C" void kernel_launch(void* const* d_in, const int* in_sizes, int n_in,
                              void* d_out, int out_size, void* d_ws,
                              size_t ws_size, hipStream_t stream) {
    const float* inputs  = (const float*)d_in[0];
    const float* alphas1 = (const float*)d_in[1];
    const float* alphas2 = (const float*)d_in[2];
    const float* W       = (const float*)d_in[3];
    char* ws = (char*)d_ws;

    __hip_bfloat16* wt  = (__hip_bfloat16*)(ws);                     // 432 KB
    __hip_bfloat16* wtR = (__hip_bfloat16*)(ws + ((size_t)1 << 19)); // 432 KB
    __hip_bfloat16* r0 = (__hip_bfloat16*)(ws + ((size_t)1 << 20));  // 18.9MB
    __hip_bfloat16* r1 = (__hip_bfloat16*)(ws + ((size_t)20 << 20));
    __hip_bfloat16* r2 = (__hip_bfloat16*)(ws + ((size_t)40 << 20));
    __hip_bfloat16* p2 = (__hip_bfloat16*)(ws + ((size_t)60 << 20)); // 16.8MB
    __hip_bfloat16* p3 = (__hip_bfloat16*)(ws + ((size_t)80 << 20)); // 16.8MB
    float* out = (float*)d_out;

    (void)hipFuncSetAttribute((const void*)conv_k<1>,
                              hipFuncAttributeMaxDynamicSharedMemorySize,
                              SMEM_BYTES);
    (void)hipFuncSetAttribute((const void*)conv_k<2>,
                              hipFuncAttributeMaxDynamicSharedMemorySize,
                              SMEM_BYTES);
    (void)hipFuncSetAttribute((const void*)conv_k<3>,
                              hipFuncAttributeMaxDynamicSharedMemorySize,
                              SMEM_BYTES);

    pre_kernel<<<864 + 128 + 4096, 256, 0, stream>>>(
        inputs, alphas1, alphas2, W, wt, wtR, r0, r1, r2);
    conv_k<1><<<512, 256, SMEM_BYTES, stream>>>(r0, wt, wtR, r1, nullptr,
                                                p2, p3);
    conv_k<2><<<512, 256, SMEM_BYTES, stream>>>(r1, wt, wtR, r2, nullptr,
                                                p2, p3);
    conv_k<3><<<512, 256, SMEM_BYTES, stream>>>(r2, wt, wtR, nullptr, out,
                                                p2, p3);
}

// Round 13
// 172.741 us; speedup vs baseline: 1.3457x; 1.3457x over previous
//
#include <hip/hip_runtime.h>
#include <hip/hip_bf16.h>

// ---------------------------------------------------------------------------
// InferCellV2 R18: R17 with single-buffered paired groups (register retreat).
// R17 post-mortem: full 1-deep pipelining on all 3 streams pushed demand to
// ~290 > the 256 cap at (256,2) -> allocator collapsed to 128 and spilled
// 60MB of scratch (convs 71us). R16 already proved the single-buffered
// paired pass fits (224 regs, ZERO scratch) - it just ran at 1 wave/SIMD.
// R18 is the untested corner: single-buffered paired (demand ~220 < 256)
// x 2 blocks/CU (2 waves/SIMD latency hiding). Only the group bodies
// change vs R17; structure/staging/chaining passed correctness 3x.
//   paired_group: Bb[8] per tap, Af[4]/Bf[4] per step (R15-verified math).
//   single_group: keeps R12's 1-deep pipeline (demand ~170, safe).
// Pre-commit: success = VGPR 200-240, zero scratch, convs 18-30us, total
// <=140. Spill or clean-but-slow -> revert R12 champion, claim plateau.
// K1(r0): paired E0(LDS-B)+E1(reg-B wtR) -> node1,p2; chain single E3 -> p3.
// K2(r1): paired E2+E4 -> node2,p3.  K3(r2): single E5 -> fp32 out.
// Geometry: 256 thr, b=blk>>2, y0=(blk&3)*8; A 10 rows 43520B + 2x16384B
// ping-pong B groups = 76288B LDS -> 2 blocks/CU; grid 512.
// ---------------------------------------------------------------------------

typedef __bf16 bf16x8 __attribute__((ext_vector_type(8)));
typedef float floatx4 __attribute__((ext_vector_type(4)));
typedef unsigned int uint32;
typedef uint32 u32x4 __attribute__((ext_vector_type(4)));
#define AS1 __attribute__((address_space(1)))

#define PADW 34
#define PIMG (PADW * PADW)
#define ROWB (PADW * 64 * 2)        // 4352 B per padded NHWC row
#define A_LDS (10 * ROWB)           // 43520 (8 out rows + 2 halo)
#define A_CHUNKS (A_LDS / 16)       // 2720 = 10*256 + 160
#define A_TAIL (A_CHUNKS - 10 * 256)// 160
#define TAPB (64 * 64 * 2)          // 8192 B per weight tap
#define GRPB (2 * TAPB)             // 16384 B per 2-tap group buffer
#define SMEM_BYTES (A_LDS + 2 * GRPB) // 76288 -> 2 blocks/CU

__device__ __forceinline__ void gld16(const char* g, char* l) {
    __builtin_amdgcn_global_load_lds(
        (const AS1 uint32*)g, (__attribute__((address_space(3))) uint32*)l,
        16, 0, 0);
}

// ---------------- fused pre-pass: weights (2 layouts) + halo + relu_pad -----
__global__ __launch_bounds__(256) void pre_kernel(
    const float* __restrict__ in, const float* __restrict__ a1,
    const float* __restrict__ a2, const float* __restrict__ W,
    __hip_bfloat16* __restrict__ wt, __hip_bfloat16* __restrict__ wtR,
    __hip_bfloat16* __restrict__ r0, __hip_bfloat16* __restrict__ r1,
    __hip_bfloat16* __restrict__ r2) {
    __shared__ float tile[32][65];
    int blk = blockIdx.x;
    int tid = threadIdx.x;

    if (blk < 864) {                 // ---- weights: scale + both layouts
        int idx = blk * 256 + tid;   // 6*9*64*64 = 221184 exact
        int i = idx & 63;
        int o = (idx >> 6) & 63;     // TRUE oc
        int rest = idx >> 12;
        int t = rest % 9;
        int l = rest / 9;
        int ji = i >> 3, jo = o >> 3;
        float ain = 0.f, aout = 0.f;
#pragma unroll
        for (int j = 0; j < 8; ++j) {
            ain  += (j >= ji) ? a1[j] : 0.f;
            aout += (j >= jo) ? a2[j] : 0.f;
        }
        float v = W[(size_t)((l * 64 + o) * 64 + i) * 9 + t] * ain * aout;
        int os = ((o & 3) << 4) + (o >> 2);      // oc-permute storage col
        size_t e = (size_t)(l * 9 + t) * 4096 + os * 64 +
                   ((((i >> 3) ^ (os & 7)) << 3) + (i & 7));
        __hip_bfloat16 bv = __float2bfloat16(v);
        wt[e] = bv;                  // layout 1 (LDS gld16 path)
        int n  = os >> 4, c15 = os & 15;
        int q  = i >> 5, quad = (i >> 3) & 3, ee = i & 7;
        int ln = (quad << 4) + c15;
        size_t e2 = (size_t)(l * 9 + t) * 4096 + (((q << 2) + n) << 9) +
                    (ln << 3) + ee;
        wtR[e2] = bv;                // layout 2 (frag-major reg path)
    } else if (blk < 992) {          // ---- zero halo ring, image b
        int b = blk - 864;
        __hip_bfloat16* bufs[3] = {r0, r1, r2};
#pragma unroll
        for (int f = 0; f < 3; ++f) {
            uint32* buf = (uint32*)(bufs[f] + (size_t)b * PIMG * 64);
            for (int idx = tid; idx < 132 * 32; idx += 256) {
                int slot = idx >> 5, u = idx & 31;
                int yy, xx;
                if (slot < 34)      { yy = 0;  xx = slot; }
                else if (slot < 68) { yy = 33; xx = slot - 34; }
                else { int s2 = slot - 68; yy = 1 + (s2 >> 1); xx = (s2 & 1) * 33; }
                buf[(size_t)(yy * PADW + xx) * 32 + u] = 0u;
            }
        }
    } else {                         // ---- relu(x) -> padded swizzled NHWC
        int rb = blk - 992;
        int b = rb >> 5, y = rb & 31;
        int x = tid & 31, c0 = tid >> 5;
        const float* ip = in + ((size_t)b * 64 * 32 + y) * 32 + x;
#pragma unroll
        for (int cc = 0; cc < 8; ++cc) {
            int c = cc * 8 + c0;
            tile[x][c] = fmaxf(ip[(size_t)c * 1024], 0.f);
        }
        __syncthreads();
        int j = tid & 7, xq = tid >> 3;
        int p = (b * PADW + y + 1) * PADW + 1 + xq;
        alignas(16) __hip_bfloat16 hv[8];
#pragma unroll
        for (int k = 0; k < 8; ++k)
            hv[k] = __float2bfloat16(tile[xq][j * 8 + k]);
        *(uint4*)((char*)r0 + (size_t)p * 128 + ((j ^ (p & 7)) << 4)) =
            *(const uint4*)hv;
    }
}

#define ZERO4(A_)                                                        \
    _Pragma("unroll") for (int m_ = 0; m_ < 4; ++m_)                     \
    _Pragma("unroll") for (int n_ = 0; n_ < 4; ++n_)                     \
        A_[m_][n_] = (floatx4){0.f, 0.f, 0.f, 0.f};

// ---------------- source-major conv kernels (256 thr, 2 blocks/CU) ---------
// Block: image b = blk>>2, strip y0 = (blk&3)*8. Wave wv(0..3): rows
// y0+2wv,+1. A-frag: l15 = px, quad*8+q*32 = in-ch. LDS-B frag: l15 =
// storage col (true oc = l15*4+n). C/D: M(pixel) = quad*4+r. Partials:
// thread-owned 128B records at (blk*256+tid)*128.
template <int MODE>
__global__ __launch_bounds__(256, 2) void conv_k(
    const __hip_bfloat16* __restrict__ Asrc,
    const __hip_bfloat16* __restrict__ wt,
    const __hip_bfloat16* __restrict__ wtR,
    __hip_bfloat16* __restrict__ nodeOut, float* __restrict__ finalOut,
    __hip_bfloat16* __restrict__ p2, __hip_bfloat16* __restrict__ p3) {
    extern __shared__ char smem[];               // A 43520 + 2x16384
    char* smemB = smem + A_LDS;
    int tid = threadIdx.x;
    int wv = tid >> 6, lane = tid & 63;
    int quad = lane >> 4, l15 = lane & 15;
    int blk = blockIdx.x;
    int b = blk >> 2, y0 = (blk & 3) << 3;
    const int Rb = b * PADW + y0;
    const size_t aOff = (size_t)Rb * PADW * 128;
    const size_t pbase = ((size_t)blk * 256 + tid) << 7;   // 128B record

    auto stage_A = [&]() {           // 10 padded rows, linear 16B DMA copy
        const char* gA = (const char*)Asrc + aOff;
#pragma unroll
        for (int it = 0; it < 11; ++it) {
            int c = it * 256 + tid;
            if (it < 10 || tid < A_TAIL)
                gld16(gA + (size_t)c * 16, smem + (it * 256 + wv * 64) * 16);
        }
    };
    // nt taps of edge l starting at tap0 -> group buffer dst
    auto stage_Bgrp = [&](int l, int tap0, int nt, char* dst) {
        const char* gB = (const char*)wt + ((size_t)l * 9 + tap0) * TAPB;
#pragma unroll
        for (int it = 0; it < 2 * nt; ++it) {
            int c = it * 256 + tid;
            gld16(gB + (size_t)c * 16, dst + (it * 256 + wv * 64) * 16);
        }
    };
    auto ldA = [&](int tl, int q, bf16x8 (&dst)[4]) {
        const int ky = tl / 3, kx = tl % 3;
#pragma unroll
        for (int m = 0; m < 4; ++m) {
            int arow = 2 * wv + (m >> 1) + ky;      // LDS row 0..9
            int apx  = ((m & 1) << 4) + l15 + kx;   // 0..33
            int R = Rb + arow;                      // global padded row
            int slot = ((q << 2) + quad) ^ ((2 * R + apx) & 7);
            dst[m] = *(const bf16x8*)(smem + arow * ROWB + apx * 128 +
                                      slot * 16);
        }
    };
    auto ldBb = [&](const char* bufB, int lt, int q, bf16x8 (&dst)[4]) {
#pragma unroll
        for (int n = 0; n < 4; ++n) {
            int o = (n << 4) + l15;                 // storage col
            int slot = ((q << 2) + quad) ^ (l15 & 7);
            dst[n] = *(const bf16x8*)(bufB + lt * TAPB + o * 128 +
                                      slot * 16);
        }
    };
    auto init_p = [&](floatx4 (&acc)[4][4], const __hip_bfloat16* p) {
#pragma unroll
        for (int c = 0; c < 8; ++c) {
            alignas(16) __hip_bfloat16 hv[8];
            *(uint4*)hv = *(const uint4*)((const char*)p + pbase + c * 16);
#pragma unroll
            for (int k = 0; k < 8; ++k) {
                int j = c * 8 + k;
                acc[j >> 4][(j >> 2) & 3][j & 3] = __bfloat162float(hv[k]);
            }
        }
    };
    auto epi_p = [&](floatx4 (&acc)[4][4], __hip_bfloat16* p) {
#pragma unroll
        for (int c = 0; c < 8; ++c) {
            alignas(16) __hip_bfloat16 hv[8];
#pragma unroll
            for (int k = 0; k < 8; ++k) {
                int j = c * 8 + k;
                hv[k] = __float2bfloat16(acc[j >> 4][(j >> 2) & 3][j & 3]);
            }
            *(uint4*)((char*)p + pbase + c * 16) = *(const uint4*)hv;
        }
    };
    auto epi_node = [&](floatx4 (&acc)[4][4], __hip_bfloat16* dst) {
#pragma unroll
        for (int m = 0; m < 4; ++m) {
            int row = y0 + 2 * wv + (m >> 1);
#pragma unroll
            for (int r = 0; r < 4; ++r) {
                int x = ((m & 1) << 4) + (quad << 2) + r;
                int p = (b * PADW + row + 1) * PADW + x + 1;
                alignas(8) __hip_bfloat16 hv[4];
#pragma unroll
                for (int n = 0; n < 4; ++n)
                    hv[n] = __float2bfloat16(fmaxf(acc[m][n][r], 0.f));
                char* d8 = (char*)dst + (size_t)p * 128 +
                           ((((l15 >> 1) ^ (p & 7)) << 4) + ((l15 & 1) << 3));
                *(uint2*)d8 = *(const uint2*)hv;
            }
        }
    };
    // paired group, SINGLE-BUFFERED (R15-verified math, R16-verified fit):
    // nt taps LDS-B from bufB -> accL; reg-B edge lR (frag-major wtR,
    // Bb[8] per tap) -> accR. Demand ~220 regs (fits 256-cap @ 2 waves/EU).
    auto paired_group = [&](const char* bufB, int lR, int t0, int nt,
                            floatx4 (&accL)[4][4], floatx4 (&accR)[4][4]) {
        const char* gR = (const char*)wtR + (size_t)lR * 9 * TAPB;
#pragma unroll
        for (int lt = 0; lt < nt; ++lt) {
            u32x4 Bb[8];
#pragma unroll
            for (int f = 0; f < 8; ++f)
                Bb[f] = *(const AS1 u32x4*)(gR + (size_t)(t0 + lt) * TAPB +
                                            (f << 10) + (lane << 4));
#pragma unroll
            for (int q = 0; q < 2; ++q) {
                bf16x8 Af[4], Bf[4];
                ldA(t0 + lt, q, Af);
                ldBb(bufB, lt, q, Bf);
                __builtin_amdgcn_s_setprio(1);
#pragma unroll
                for (int m = 0; m < 4; ++m)
#pragma unroll
                    for (int n = 0; n < 4; ++n)
                        accL[m][n] = __builtin_amdgcn_mfma_f32_16x16x32_bf16(
                            Af[m], Bf[n], accL[m][n], 0, 0, 0);
#pragma unroll
                for (int n = 0; n < 4; ++n) {
                    bf16x8 Br = __builtin_bit_cast(bf16x8, Bb[(q << 2) + n]);
#pragma unroll
                    for (int m = 0; m < 4; ++m)
                        accR[m][n] = __builtin_amdgcn_mfma_f32_16x16x32_bf16(
                            Af[m], Br, accR[m][n], 0, 0, 0);
                }
                __builtin_amdgcn_s_setprio(0);
            }
        }
    };
    // single-edge group with R12's verified 1-deep pipeline (demand ~170).
    auto single_group = [&](const char* bufB, int t0, int nt,
                            floatx4 (&acc)[4][4]) {
        bf16x8 Af[2][4], Bf[2][4];
        ldA(t0, 0, Af[0]);
        ldBb(bufB, 0, 0, Bf[0]);
#pragma unroll
        for (int st = 0; st < 2 * nt; ++st) {
            const int pb = st & 1;
            if (st + 1 < 2 * nt) {
                ldA(t0 + ((st + 1) >> 1), (st + 1) & 1, Af[pb ^ 1]);
                ldBb(bufB, (st + 1) >> 1, (st + 1) & 1, Bf[pb ^ 1]);
            }
            __builtin_amdgcn_s_setprio(1);
#pragma unroll
            for (int m = 0; m < 4; ++m)
#pragma unroll
                for (int n = 0; n < 4; ++n)
                    acc[m][n] = __builtin_amdgcn_mfma_f32_16x16x32_bf16(
                        Af[pb][m], Bf[pb][n], acc[m][n], 0, 0, 0);
            __builtin_amdgcn_s_setprio(0);
        }
    };

    if constexpr (MODE == 1) {
        stage_A();
        stage_Bgrp(0, 0, 2, smemB);          // E0 g0 -> buf0
        __syncthreads();
        floatx4 aT[4][4], aX[4][4];
        ZERO4(aT); ZERO4(aX);
#pragma unroll
        for (int g = 0; g < 5; ++g) {        // E0/E1 paired phase
            char* cur = smemB + (g & 1) * GRPB;
            char* nxt = smemB + ((g + 1) & 1) * GRPB;
            if (g < 4) stage_Bgrp(0, 2 * (g + 1), (g + 1 == 4) ? 1 : 2, nxt);
            else       stage_Bgrp(3, 0, 2, nxt);   // chain into E3 phase
            __builtin_amdgcn_sched_barrier(0);
            paired_group(cur, 1, 2 * g, (g == 4) ? 1 : 2, aT, aX);
            __syncthreads();                 // next group resident
        }
        epi_node(aT, nodeOut);               // node1 = relu -> r1
        epi_p(aX, p2);
        floatx4 aY[4][4];
        ZERO4(aY);
#pragma unroll
        for (int g = 0; g < 5; ++g) {        // E3 single phase
            char* cur = smemB + ((5 + g) & 1) * GRPB;
            char* nxt = smemB + ((6 + g) & 1) * GRPB;
            if (g < 4) stage_Bgrp(3, 2 * (g + 1), (g + 1 == 4) ? 1 : 2, nxt);
            __builtin_amdgcn_sched_barrier(0);
            single_group(cur, 2 * g, (g == 4) ? 1 : 2, aY);
            if (g < 4) __syncthreads();
        }
        epi_p(aY, p3);
    } else if constexpr (MODE == 2) {
        stage_A();
        stage_Bgrp(2, 0, 2, smemB);          // E2 g0 -> buf0
        __syncthreads();
        floatx4 aX[4][4], aY[4][4];
        init_p(aX, p2);
        init_p(aY, p3);
#pragma unroll
        for (int g = 0; g < 5; ++g) {
            char* cur = smemB + (g & 1) * GRPB;
            char* nxt = smemB + ((g + 1) & 1) * GRPB;
            if (g < 4) stage_Bgrp(2, 2 * (g + 1), (g + 1 == 4) ? 1 : 2, nxt);
            __builtin_amdgcn_sched_barrier(0);
            paired_group(cur, 4, 2 * g, (g == 4) ? 1 : 2, aX, aY);
            if (g < 4) __syncthreads();
        }
        epi_node(aX, nodeOut);               // node2 = relu -> r2
        epi_p(aY, p3);
    } else {
        stage_A();
        stage_Bgrp(5, 0, 2, smemB);          // E5 g0 -> buf0
        __syncthreads();
        floatx4 aY[4][4];
        init_p(aY, p3);
#pragma unroll
        for (int g = 0; g < 5; ++g) {
            char* cur = smemB + (g & 1) * GRPB;
            char* nxt = smemB + ((g + 1) & 1) * GRPB;
            if (g < 4) stage_Bgrp(5, 2 * (g + 1), (g + 1 == 4) ? 1 : 2, nxt);
            __builtin_amdgcn_sched_barrier(0);
            single_group(cur, 2 * g, (g == 4) ? 1 : 2, aY);
            if (g < 4) __syncthreads();
        }
        // fp32 NCHW epilogue (oc = l15*4+n, verified R11/R12)
#pragma unroll
        for (int m = 0; m < 4; ++m) {
            int row = y0 + 2 * wv + (m >> 1);
#pragma unroll
            for (int n = 0; n < 4; ++n) {
                int o = (l15 << 2) + n;
                *(floatx4*)(finalOut +
                            (((size_t)b * 64 + o) * 32 + row) * 32 +
                            ((m & 1) << 4) + (quad << 2)) = aY[m][n];
            }
        }
    }
}

// ---------------------------------------------------------------------------
extern "C" void kernel_launch(void* const* d_in, const int* in_sizes, int n_in,
                              void* d_out, int out_size, void* d_ws,
                              size_t ws_size, hipStream_t stream) {
    const float* inputs  = (const float*)d_in[0];
    const float* alphas1 = (const float*)d_in[1];
    const float* alphas2 = (const float*)d_in[2];
    const float* W       = (const float*)d_in[3];
    char* ws = (char*)d_ws;

    __hip_bfloat16* wt  = (__hip_bfloat16*)(ws);                     // 432 KB
    __hip_bfloat16* wtR = (__hip_bfloat16*)(ws + ((size_t)1 << 19)); // 432 KB
    __hip_bfloat16* r0 = (__hip_bfloat16*)(ws + ((size_t)1 << 20));  // 18.9MB
    __hip_bfloat16* r1 = (__hip_bfloat16*)(ws + ((size_t)20 << 20));
    __hip_bfloat16* r2 = (__hip_bfloat16*)(ws + ((size_t)40 << 20));
    __hip_bfloat16* p2 = (__hip_bfloat16*)(ws + ((size_t)60 << 20)); // 16.8MB
    __hip_bfloat16* p3 = (__hip_bfloat16*)(ws + ((size_t)80 << 20)); // 16.8MB
    float* out = (float*)d_out;

    (void)hipFuncSetAttribute((const void*)conv_k<1>,
                              hipFuncAttributeMaxDynamicSharedMemorySize,
                              SMEM_BYTES);
    (void)hipFuncSetAttribute((const void*)conv_k<2>,
                              hipFuncAttributeMaxDynamicSharedMemorySize,
                              SMEM_BYTES);
    (void)hipFuncSetAttribute((const void*)conv_k<3>,
                              hipFuncAttributeMaxDynamicSharedMemorySize,
                              SMEM_BYTES);

    pre_kernel<<<864 + 128 + 4096, 256, 0, stream>>>(
        inputs, alphas1, alphas2, W, wt, wtR, r0, r1, r2);
    conv_k<1><<<512, 256, SMEM_BYTES, stream>>>(r0, wt, wtR, r1, nullptr,
                                                p2, p3);
    conv_k<2><<<512, 256, SMEM_BYTES, stream>>>(r1, wt, wtR, r2, nullptr,
                                                p2, p3);
    conv_k<3><<<512, 256, SMEM_BYTES, stream>>>(r2, wt, wtR, nullptr, out,
                                                p2, p3);
}